// Round 3
// baseline (459.924 us; speedup 1.0000x reference)
//
#include <hip/hip_runtime.h>
#include <cstdint>
#include <cstddef>

// out[m,n] = scale[m]*wscale[n]*(sum_k q[m,k]*w8[n,k] - azp[m]*azp_adj[n]) + bias[n]
// M=8192, K=4096, N=4096. Exact int8 path; absmax from fp32 epilogue only.

#define M_DIM 8192
#define K_DIM 4096
#define N_DIM 4096

typedef int v4i __attribute__((ext_vector_type(4)));

// ---------------------------------------------------------------------------
// Kernel 1: per-token asymmetric quantization (UNCHANGED from round 2 for
// clean attribution of the gemm pipeline change).
// ---------------------------------------------------------------------------
__global__ __launch_bounds__(256) void quant_kernel(
    const float* __restrict__ x, signed char* __restrict__ q,
    float* __restrict__ scale_out, int* __restrict__ azp_out)
{
    const int m = blockIdx.x;
    const int t = threadIdx.x;
    const float4* row4 = (const float4*)(x + (size_t)m * K_DIM);

    float4 v[4];
    float mx = -3.4e38f, mn = 3.4e38f;
#pragma unroll
    for (int i = 0; i < 4; ++i) {
        v[i] = row4[i * 256 + t];
        mx = fmaxf(mx, fmaxf(fmaxf(v[i].x, v[i].y), fmaxf(v[i].z, v[i].w)));
        mn = fminf(mn, fminf(fminf(v[i].x, v[i].y), fminf(v[i].z, v[i].w)));
    }
#pragma unroll
    for (int off = 32; off; off >>= 1) {
        mx = fmaxf(mx, __shfl_down(mx, off));
        mn = fminf(mn, __shfl_down(mn, off));
    }
    __shared__ float smx[4], smn[4];
    if ((t & 63) == 0) { smx[t >> 6] = mx; smn[t >> 6] = mn; }
    __syncthreads();
    mx = fmaxf(fmaxf(smx[0], smx[1]), fmaxf(smx[2], smx[3]));
    mn = fminf(fminf(smn[0], smn[1]), fminf(smn[2], smn[3]));

    const float scale = (mx - mn) / 255.0f;
    const int azp = (int)rintf(-128.0f - mn / scale);
    if (t == 0) { scale_out[m] = scale; azp_out[m] = azp; }

    int* qrow = (int*)(q + (size_t)m * K_DIM);
    const float* vf = (const float*)v;
#pragma unroll
    for (int i = 0; i < 4; ++i) {
        int b[4];
#pragma unroll
        for (int j = 0; j < 4; ++j) {
            int qv = (int)rintf(vf[4 * i + j] / scale) + azp;
            qv = qv < -128 ? -128 : (qv > 127 ? 127 : qv);
            b[j] = qv;
        }
        qrow[i * 256 + t] =
            (b[0] & 255) | ((b[1] & 255) << 8) | ((b[2] & 255) << 16) | ((b[3] & 255) << 24);
    }
}

// ---------------------------------------------------------------------------
// Kernel 2: weight prep (UNCHANGED from round 2).
// ---------------------------------------------------------------------------
__global__ __launch_bounds__(256) void wprep_kernel(
    const int* __restrict__ w, signed char* __restrict__ w8, int* __restrict__ azp_adj)
{
    const int n = blockIdx.x;
    const int t = threadIdx.x;
    const int4* row = (const int4*)(w + (size_t)n * K_DIM);
    int* w8row = (int*)(w8 + (size_t)n * K_DIM);
    int sum = 0;
#pragma unroll
    for (int i = 0; i < 4; ++i) {
        int4 a = row[i * 256 + t];
        sum += a.x + a.y + a.z + a.w;
        w8row[i * 256 + t] =
            (a.x & 255) | ((a.y & 255) << 8) | ((a.z & 255) << 16) | ((a.w & 255) << 24);
    }
#pragma unroll
    for (int off = 32; off; off >>= 1) sum += __shfl_down(sum, off);
    __shared__ int ssum[4];
    if ((t & 63) == 0) ssum[t >> 6] = sum;
    __syncthreads();
    if (t == 0) azp_adj[n] = ssum[0] + ssum[1] + ssum[2] + ssum[3];
}

// ---------------------------------------------------------------------------
// Kernel 3: int8 GEMM, PIPELINED single-barrier K-loop.
// 128x128 tile, BK=64, 4 waves x (4x4) mfma_i32_16x16x64_i8, XOR-swizzled LDS
// (round-2 verified: SQ_LDS_BANK_CONFLICT = 0).
//
// Pipeline (per iter i): [s_waitcnt vmcnt(0); s_barrier] — waits only the
// prefetch issued at iter i-1 (a whole iteration of slack) — then ISSUE the
// next tile's global_load_lds into buf nxt, then ds_read+mfma on buf cur.
// Hazard proof: writes to nxt at iter i are issued after barrier(i); every
// wave's ds_reads of nxt (iter i-1, as cur) retired before that wave reached
// barrier(i) (their data was consumed by iter i-1's mfmas). One barrier/iter.
// Raw s_barrier via asm w/ memory clobber — avoids __syncthreads' compiler-
// emitted vmcnt(0)-after-issue drain that serialized round 2 (937 cyc/iter
// measured ~= 327 mfma + 385 lds + 290 staging, zero overlap).
// ---------------------------------------------------------------------------
__device__ __forceinline__ void async_copy16(const signed char* g, signed char* l) {
    __builtin_amdgcn_global_load_lds(
        (const __attribute__((address_space(1))) void*)g,
        (__attribute__((address_space(3))) void*)l, 16, 0, 0);
}

__global__ __launch_bounds__(256) void gemm_kernel(
    const signed char* __restrict__ A,   // [M,K]
    const signed char* __restrict__ B,   // [N,K]
    const float* __restrict__ scale, const int* __restrict__ azp,
    const int* __restrict__ azp_adj, const float* __restrict__ wscale,
    const float* __restrict__ bias, float* __restrict__ out)
{
    __shared__ signed char sA[2][128 * 64];
    __shared__ signed char sB[2][128 * 64];

    const int t = threadIdx.x;
    const int wave = t >> 6;
    const int lane = t & 63;
    const int quad = lane >> 4;
    const int r16 = lane & 15;

    const int bm = blockIdx.y * 128;
    const int bn = blockIdx.x * 128;
    const int wm = (wave >> 1) * 64;
    const int wn = (wave & 1) * 64;

    v4i acc[4][4];
#pragma unroll
    for (int i = 0; i < 4; ++i)
#pragma unroll
        for (int j = 0; j < 4; ++j) acc[i][j] = (v4i){0, 0, 0, 0};

    // staging: thread t fills LDS granule t (row=t>>2, colL=t&3) with global
    // column colG = (t&3) ^ ((t>>3)&3)  (XOR swizzle, row-periodic mod 8).
    const int srow = t >> 2;
    const int scol = ((t & 3) ^ ((t >> 3) & 3)) * 16;
    const signed char* ag0 = A + (size_t)(bm + srow) * K_DIM + scol;
    const signed char* ag1 = A + (size_t)(bm + 64 + srow) * K_DIM + scol;
    const signed char* bg0 = B + (size_t)(bn + srow) * K_DIM + scol;
    const signed char* bg1 = B + (size_t)(bn + 64 + srow) * K_DIM + scol;

    // prologue: stage tile 0 into buffer 0
    async_copy16(ag0, sA[0] + t * 16);
    async_copy16(ag1, sA[0] + 4096 + t * 16);
    async_copy16(bg0, sB[0] + t * 16);
    async_copy16(bg1, sB[0] + 4096 + t * 16);

#pragma unroll 2
    for (int i = 0; i < 64; ++i) {
        const int cur = i & 1;
        const int nxt = cur ^ 1;

        // wait own prefetch (issued one full iter ago), then workgroup barrier
        asm volatile("s_waitcnt vmcnt(0)\n\ts_barrier" ::: "memory");

        // issue next tile's staging immediately — overlaps this iter's compute
        if (i < 63) {
            const int kn = (i + 1) << 6;
            async_copy16(ag0 + kn, sA[nxt] + t * 16);
            async_copy16(ag1 + kn, sA[nxt] + 4096 + t * 16);
            async_copy16(bg0 + kn, sB[nxt] + t * 16);
            async_copy16(bg1 + kn, sB[nxt] + 4096 + t * 16);
        }

        const v4i* sA4 = (const v4i*)sA[cur];
        const v4i* sB4 = (const v4i*)sB[cur];
        v4i af[4], bf[4];
#pragma unroll
        for (int j = 0; j < 4; ++j) {
            const int ra = wm + j * 16 + r16;
            const int rb = wn + j * 16 + r16;
            af[j] = sA4[ra * 4 + (quad ^ ((ra >> 1) & 3))];
            bf[j] = sB4[rb * 4 + (quad ^ ((rb >> 1) & 3))];
        }
#pragma unroll
        for (int ii = 0; ii < 4; ++ii)
#pragma unroll
            for (int jj = 0; jj < 4; ++jj)
                acc[ii][jj] = __builtin_amdgcn_mfma_i32_16x16x64_i8(af[ii], bf[jj], acc[ii][jj], 0, 0, 0);
    }

    // epilogue: out = scale[m]*wscale[n]*(acc - azp[m]*adj[n]) + bias[n]
#pragma unroll
    for (int i = 0; i < 4; ++i) {
        const int mbase = bm + wm + i * 16 + quad * 4;
        float sm[4]; int am[4];
#pragma unroll
        for (int r = 0; r < 4; ++r) { sm[r] = scale[mbase + r]; am[r] = azp[mbase + r]; }
#pragma unroll
        for (int j = 0; j < 4; ++j) {
            const int n = bn + wn + j * 16 + r16;
            const float wsn = wscale[n];
            const int adjn = azp_adj[n];
            const float bn_ = bias[n];
#pragma unroll
            for (int r = 0; r < 4; ++r) {
                const int c = acc[i][j][r] - am[r] * adjn;
                out[(size_t)(mbase + r) * N_DIM + n] = sm[r] * wsn * (float)c + bn_;
            }
        }
    }
}

// ---------------------------------------------------------------------------
extern "C" void kernel_launch(void* const* d_in, const int* in_sizes, int n_in,
                              void* d_out, int out_size, void* d_ws, size_t ws_size,
                              hipStream_t stream) {
    const float* x      = (const float*)d_in[0];
    const int*   w      = (const int*)d_in[1];
    const float* wscale = (const float*)d_in[2];
    const float* bias   = (const float*)d_in[3];
    float* out = (float*)d_out;

    char* ws = (char*)d_ws;
    signed char* q8  = (signed char*)ws;                         // 32 MiB
    signed char* w8  = (signed char*)(ws + 33554432);            // 16 MiB
    float* scl       = (float*)(ws + 50331648);                  // 32 KiB
    int*   azp       = (int*)(ws + 50331648 + 32768);            // 32 KiB
    int*   adj       = (int*)(ws + 50331648 + 65536);            // 16 KiB

    quant_kernel<<<M_DIM, 256, 0, stream>>>(x, q8, scl, azp);
    wprep_kernel<<<N_DIM, 256, 0, stream>>>(w, w8, adj);
    dim3 grid(N_DIM / 128, M_DIM / 128);
    gemm_kernel<<<grid, 256, 0, stream>>>(q8, w8, scl, azp, adj, wscale, bias, out);
}